// Round 10
// baseline (144.599 us; speedup 1.0000x reference)
//
#include <hip/hip_runtime.h>

// (B, D, T, V) = (16, 128, 4096, 1024)
#define B_ 16
#define D_ 128
#define T_ 4096
#define V_ 1024

typedef _Float16 half8 __attribute__((ext_vector_type(8)));
typedef float float4v __attribute__((ext_vector_type(4)));

// ws layout:
//   [0,     4096) : chsq (V floats) = 0.5*|c|^2
//   [4096, 528384): Bc — 32 chunks x 16 KB, each chunk the EXACT LDS image:
//     chunk c = v in [c*32, c*32+32):
//       byte = c*16384 + hl*8192 + kt*2048 + ntl*1024 + (q*16 + ln)*16
//       fragment (v = c*32+ntl*16+ln, k = kt*32+q*8 .. +8), hl: 0=hi,1=lo
//     => LDS read lane-linear (lane L reads +L*16): zero bank conflicts (R9 ✓)
//
// LESSONS:
//  R3/R4: tight launch_bounds at 256-thr blocks spills through HBM (FETCH
//    356-853MB). R10 avoids the cliff structurally: (128,1) = 512-reg budget.
//  R5: hipLaunchCooperativeKernel fails under this harness.
//  R8: measured time = SUM of pipes (MFMA 24.8 + B-LDS 20.5 + VALU 16.5 µs):
//    2 waves/SIMD stall in lockstep; B-LDS traffic scales with waves/CU.
//  R9: lane-linear B image kills conflicts (4.3M->131k) — keep. Runtime-indexed
//    dual acc sets regress (select chains) — drop.
//  R10: wave-M=64 (2-wave blocks, A hi+lo in 128 VGPRs) halves B-LDS traffic
//    and gives 96 independent MFMAs/chunk of in-wave ILP.

// Fused: split codebook into f16 hi/lo fragments (lane-linear image) + chsq.
__global__ __launch_bounds__(256) void split_csq_kernel(const float* __restrict__ cb,
                                                        char* __restrict__ Bc,
                                                        float* __restrict__ chsq) {
    const int g = blockIdx.x * 256 + threadIdx.x;  // 16384 threads
    const int v = g >> 4;
    const int k0 = (g & 15) << 3;
    const float* src = cb + (size_t)v * D_ + k0;
    half8 h, l;
    float s = 0.f;
#pragma unroll
    for (int j = 0; j < 8; ++j) {
        float c = src[j];
        _Float16 ch = (_Float16)c;
        h[j] = ch;
        l[j] = (_Float16)((c - (float)ch) * 2048.0f);
        s = fmaf(c, c, s);
    }
    const int kt = k0 >> 5;        // 32-k tile
    const int q = (k0 >> 3) & 3;   // 8-k sub
    const int c = v >> 5;          // 32-v chunk
    const int ntl = (v >> 4) & 1;  // 16-v n-tile
    const int ln = v & 15;
    const size_t off =
        (size_t)c * 16384 + kt * 2048 + ntl * 1024 + (size_t)(q * 16 + ln) * 16;
    *(half8*)(Bc + off) = h;
    *(half8*)(Bc + off + 8192) = l;
#pragma unroll
    for (int o = 1; o < 16; o <<= 1) s += __shfl_xor(s, o, 64);
    if ((g & 15) == 0) chsq[v] = 0.5f * s;
}

// Async 16B/lane global->LDS copy; HW scatters lane i to lds + i*16.
__device__ __forceinline__ void dma16(const char* g, char* lds) {
    __builtin_amdgcn_global_load_lds(
        (const __attribute__((address_space(1))) unsigned int*)g,
        (__attribute__((address_space(3))) unsigned int*)lds, 16, 0, 0);
}

// Stage one 16 KB chunk: 16 segs of 1 KB, 8 per wave (2 waves).
__device__ __forceinline__ void dma_chunk(char* ldsbuf, const char* Bc, int c, int wq,
                                          int tl) {
#pragma unroll
    for (int j = 0; j < 8; ++j) {
        const int seg = wq * 8 + j;
        dma16(Bc + (size_t)c * 16384 + seg * 1024 + tl * 16, ldsbuf + seg * 1024);
    }
}

// Main kernel: block = 128 thr = 2 waves; block tile = 128 t x all 1024 v.
// Wave wq owns t-rows [wq*64, +64) (mt=4), A hi+lo fully register-resident
// (128 VGPRs; legal at (128,1) = 512-reg budget, 1 wave/SIMD, 2 blocks/CU by
// LDS). All waves sweep all v in 32 chunks from the lane-linear LDS dbuf.
// Numerics proven (absmax 0):
//   acc1 = sum_k xh*ch ; acc2 = sum_k (xh*cl' + xl'*ch)  (lo pre-scaled 2048)
//   score = 0.5|c|^2 - (acc1 + acc2/2048); running argmin, ties -> lowest v.
__global__ __launch_bounds__(128, 1) void vq_mfma(const float* __restrict__ latents,
                                                  const float* __restrict__ codebook,
                                                  const float* __restrict__ chsq,
                                                  const char* __restrict__ Bc,
                                                  float* __restrict__ out_codes,
                                                  float* __restrict__ out_q) {
    // union: A-stage (128x136 halves x2 = 69632 B) then B double-buffer (2x16384)
    __shared__ __align__(16) char smem[69632];
    __shared__ float sChsq[V_];
    __shared__ int scode[128];

    const int tid = threadIdx.x;
    const int tl = tid & 63;
    const int wq = tid >> 6;       // 0..1
    const int ln = tid & 15;       // MFMA col (n) / A row (m)
    const int q = (tid >> 4) & 3;  // quad
    const int b = blockIdx.x >> 5;           // 32 t-tiles of 128 per batch entry
    const int t00 = (blockIdx.x & 31) << 7;  // t-tile start

    _Float16* AhS = (_Float16*)smem;  // [128][136] (+8 pad)
    _Float16* AlS = AhS + 128 * 136;

    // ---- stage chsq into LDS ----
#pragma unroll
    for (int i = 0; i < V_ / 128; ++i) sChsq[tid + i * 128] = chsq[tid + i * 128];

    // ---- stage A tile (128 t x 128 d), f16 split, [t][k] rows ----
#pragma unroll
    for (int th = 0; th < 2; ++th) {
        const int row = th * 64 + tl;
        const float* xp = latents + (size_t)b * D_ * T_ + t00 + row;
#pragma unroll
        for (int i = 0; i < 8; ++i) {
            const int d0 = wq * 64 + i * 8;
            float x[8];
#pragma unroll
            for (int j = 0; j < 8; ++j) x[j] = xp[(size_t)(d0 + j) * T_];
            half8 h, l;
#pragma unroll
            for (int j = 0; j < 8; ++j) {
                _Float16 xh = (_Float16)x[j];
                h[j] = xh;
                l[j] = (_Float16)((x[j] - (float)xh) * 2048.0f);
            }
            *(half8*)(AhS + row * 136 + d0) = h;
            *(half8*)(AlS + row * 136 + d0) = l;
        }
    }
    __syncthreads();

    // ---- extract A fragments to registers (once): wave owns rows wq*64..+64 ----
    half8 ah[4][4], al[4][4];  // [kt][mt] : 128 VGPRs
#pragma unroll
    for (int kt = 0; kt < 4; ++kt)
#pragma unroll
        for (int mt = 0; mt < 4; ++mt) {
            const int row = wq * 64 + mt * 16 + ln;
            ah[kt][mt] = *(const half8*)(AhS + row * 136 + kt * 32 + q * 8);
            al[kt][mt] = *(const half8*)(AlS + row * 136 + kt * 32 + q * 8);
        }
    __syncthreads();  // A region dead -> reuse as B double-buffer

    char* Bb = smem;  // [2][16384]

    float bestF[4][4];
    int bestv[4][4];
#pragma unroll
    for (int mt = 0; mt < 4; ++mt)
#pragma unroll
        for (int r = 0; r < 4; ++r) {
            bestF[mt][r] = 3.0e38f;
            bestv[mt][r] = 0;
        }

    // ---- prologue: DMA chunk 0 into buf 0; barrier drains vmcnt ----
    dma_chunk(Bb, Bc, 0, wq, tl);
    __syncthreads();

    for (int c = 0; c < 32; ++c) {
        if (c + 1 < 32) dma_chunk(Bb + ((c + 1) & 1) * 16384, Bc, c + 1, wq, tl);

        const char* buf = Bb + (c & 1) * 16384;
        float4v acc1[4][2], acc2[4][2];
#pragma unroll
        for (int mt = 0; mt < 4; ++mt)
#pragma unroll
            for (int ntl = 0; ntl < 2; ++ntl) {
                acc1[mt][ntl] = (float4v){0.f, 0.f, 0.f, 0.f};
                acc2[mt][ntl] = (float4v){0.f, 0.f, 0.f, 0.f};
            }
#pragma unroll
        for (int kt = 0; kt < 4; ++kt) {
            half8 bh[2], bl[2];
#pragma unroll
            for (int ntl = 0; ntl < 2; ++ntl) {
                const int o = kt * 2048 + ntl * 1024 + tl * 16;  // lane-linear
                bh[ntl] = *(const half8*)(buf + o);
                bl[ntl] = *(const half8*)(buf + 8192 + o);
            }
#pragma unroll
            for (int ntl = 0; ntl < 2; ++ntl)
#pragma unroll
                for (int mt = 0; mt < 4; ++mt) {
                    acc1[mt][ntl] = __builtin_amdgcn_mfma_f32_16x16x32_f16(
                        ah[kt][mt], bh[ntl], acc1[mt][ntl], 0, 0, 0);
                    acc2[mt][ntl] = __builtin_amdgcn_mfma_f32_16x16x32_f16(
                        ah[kt][mt], bl[ntl], acc2[mt][ntl], 0, 0, 0);
                    acc2[mt][ntl] = __builtin_amdgcn_mfma_f32_16x16x32_f16(
                        al[kt][mt], bh[ntl], acc2[mt][ntl], 0, 0, 0);
                }
        }
        // immediate fold (compile-time indices); ntl=0 first => lower n on ties
#pragma unroll
        for (int ntl = 0; ntl < 2; ++ntl) {
            const int n = c * 32 + ntl * 16 + ln;
            const float csq = sChsq[n];
#pragma unroll
            for (int mt = 0; mt < 4; ++mt)
#pragma unroll
                for (int r = 0; r < 4; ++r) {
                    const float score =
                        csq - (acc1[mt][ntl][r] + acc2[mt][ntl][r] * (1.0f / 2048.0f));
                    if (score < bestF[mt][r]) {  // strict < => lowest v on ties
                        bestF[mt][r] = score;
                        bestv[mt][r] = n;
                    }
                }
        }
        __syncthreads();  // drain DMA(c+1) + release buf for chunk c+2
    }

    // cross-lane argmin over the 16-col group; ties -> lowest v
#pragma unroll
    for (int off = 1; off < 16; off <<= 1) {
#pragma unroll
        for (int mt = 0; mt < 4; ++mt)
#pragma unroll
            for (int r = 0; r < 4; ++r) {
                const float of = __shfl_xor(bestF[mt][r], off, 64);
                const int ov = __shfl_xor(bestv[mt][r], off, 64);
                if (of < bestF[mt][r] || (of == bestF[mt][r] && ov < bestv[mt][r])) {
                    bestF[mt][r] = of;
                    bestv[mt][r] = ov;
                }
            }
    }

    // per-wave complete argmin: lanes ln==0 publish rows m = wq*64+mt*16+q*4+r
    if (ln == 0) {
#pragma unroll
        for (int mt = 0; mt < 4; ++mt)
#pragma unroll
            for (int r = 0; r < 4; ++r) {
                const int m = wq * 64 + mt * 16 + q * 4 + r;
                scode[m] = bestv[mt][r];
                out_codes[(size_t)b * T_ + t00 + m] = (float)bestv[mt][r];
            }
    }
    __syncthreads();

    // gather-write quantized[b, d, t00+row] = codebook[code, d]; coalesced
#pragma unroll
    for (int th = 0; th < 2; ++th) {
        const int row = th * 64 + tl;
        const int code = scode[row];
        const float* crow = codebook + (size_t)code * D_;
        float* qp = out_q + (size_t)b * D_ * T_ + t00 + row;
#pragma unroll
        for (int i = 0; i < 64; ++i) {
            const int d = wq * 64 + i;
            qp[(size_t)d * T_] = crow[d];
        }
    }
}

extern "C" void kernel_launch(void* const* d_in, const int* in_sizes, int n_in,
                              void* d_out, int out_size, void* d_ws, size_t ws_size,
                              hipStream_t stream) {
    const float* latents = (const float*)d_in[0];   // (B, D, T) f32
    const float* codebook = (const float*)d_in[1];  // (V, D) f32

    float* out_codes = (float*)d_out;        // (B, T) codes as f32 values
    float* out_q = (float*)d_out + B_ * T_;  // (B, D, T) quantized f32

    float* chsq = (float*)d_ws;
    char* Bc = (char*)d_ws + 4096;  // 512 KB lane-linear f16 hi/lo image

    split_csq_kernel<<<(V_ * 16) / 256, 256, 0, stream>>>(codebook, Bc, chsq);
    vq_mfma<<<(B_ * T_) / 128, 128, 0, stream>>>(latents, codebook, chsq, Bc, out_codes,
                                                 out_q);
}

// Round 11
// 130.772 us; speedup vs baseline: 1.1057x; 1.1057x over previous
//
#include <hip/hip_runtime.h>

// (B, D, T, V) = (16, 128, 4096, 1024)
#define B_ 16
#define D_ 128
#define T_ 4096
#define V_ 1024

typedef _Float16 half8 __attribute__((ext_vector_type(8)));
typedef float float4v __attribute__((ext_vector_type(4)));

// ws layout:
//   [0,     4096) : chsq (V floats) = 0.5*|c|^2
//   [4096, 528384): Bc — 32 chunks x 16 KB, each chunk the EXACT LDS image:
//     chunk c = v in [c*32, c*32+32):
//       byte = c*16384 + hl*8192 + kt*2048 + ntl*1024 + (q*16 + ln)*16
//       fragment (v = c*32+ntl*16+ln, k = kt*32+q*8 .. +8), hl: 0=hi,1=lo
//     => LDS read lane-linear (lane L reads +L*16): zero bank conflicts (R9 ✓)
//
// LESSONS:
//  R3/R4: tight launch_bounds on 256-thr blocks spills through HBM (FETCH
//    356-853MB signature). (256,2) is the proven no-spill point.
//  R5: hipLaunchCooperativeKernel fails under this harness.
//  R9: lane-linear B image kills conflicts — keep. RUNTIME-indexed acc sets
//    regress (select chains, VGPR 88->112) — all acc indices compile-time.
//  R10: 1 wave/SIMD (128-thr blocks) exposes all latency — min 2 waves/SIMD.
//  R11: R8 shape + lane-linear B + paired chunks (32KB dbuf, 16 barriers) +
//    compile-time dual acc sets so foldA co-issues with chunk-B MFMAs (m114).

// Fused: split codebook into f16 hi/lo fragments (lane-linear image) + chsq.
__global__ __launch_bounds__(256) void split_csq_kernel(const float* __restrict__ cb,
                                                        char* __restrict__ Bc,
                                                        float* __restrict__ chsq) {
    const int g = blockIdx.x * 256 + threadIdx.x;  // 16384 threads
    const int v = g >> 4;
    const int k0 = (g & 15) << 3;
    const float* src = cb + (size_t)v * D_ + k0;
    half8 h, l;
    float s = 0.f;
#pragma unroll
    for (int j = 0; j < 8; ++j) {
        float c = src[j];
        _Float16 ch = (_Float16)c;
        h[j] = ch;
        l[j] = (_Float16)((c - (float)ch) * 2048.0f);
        s = fmaf(c, c, s);
    }
    const int kt = k0 >> 5;        // 32-k tile
    const int q = (k0 >> 3) & 3;   // 8-k sub
    const int c = v >> 5;          // 32-v chunk
    const int ntl = (v >> 4) & 1;  // 16-v n-tile
    const int ln = v & 15;
    const size_t off =
        (size_t)c * 16384 + kt * 2048 + ntl * 1024 + (size_t)(q * 16 + ln) * 16;
    *(half8*)(Bc + off) = h;
    *(half8*)(Bc + off + 8192) = l;
#pragma unroll
    for (int o = 1; o < 16; o <<= 1) s += __shfl_xor(s, o, 64);
    if ((g & 15) == 0) chsq[v] = 0.5f * s;
}

// Async 16B/lane global->LDS copy; HW scatters lane i to lds + i*16.
__device__ __forceinline__ void dma16(const char* g, char* lds) {
    __builtin_amdgcn_global_load_lds(
        (const __attribute__((address_space(1))) unsigned int*)g,
        (__attribute__((address_space(3))) unsigned int*)lds, 16, 0, 0);
}

// Stage one 32 KB chunk-PAIR (chunks 2p, 2p+1 are contiguous in Bc):
// 32 segs of 1 KB, 8 per wave (4 waves).
__device__ __forceinline__ void dma_pair(char* ldsbuf, const char* Bc, int p, int wq,
                                         int tl) {
#pragma unroll
    for (int j = 0; j < 8; ++j) {
        const int seg = wq * 8 + j;
        dma16(Bc + (size_t)p * 32768 + seg * 1024 + tl * 16, ldsbuf + seg * 1024);
    }
}

// Main kernel: block = 256 thr = 4 waves; block tile = 128 t x all 1024 v.
// Wave wq owns t-rows [wq*32, +32) (mt=2), A hi+lo register-resident (64 VGPR).
// All waves sweep all v in 16 chunk-PAIRS from a 2x32KB lane-linear LDS dbuf.
// Per pair: MFMA chunk A -> MFMA chunk B (independent) -> fold A (co-issues
// with B's MFMAs) -> fold B -> barrier. All acc indices compile-time.
// Numerics proven (absmax 0):
//   acc1 = sum_k xh*ch ; acc2 = sum_k (xh*cl' + xl'*ch)  (lo pre-scaled 2048)
//   score = 0.5|c|^2 - (acc1 + acc2/2048); running argmin, ties -> lowest v.
__global__ __launch_bounds__(256, 2) void vq_mfma(const float* __restrict__ latents,
                                                  const float* __restrict__ codebook,
                                                  const float* __restrict__ chsq,
                                                  const char* __restrict__ Bc,
                                                  float* __restrict__ out_codes,
                                                  float* __restrict__ out_q) {
    // union: A-stage (128x136 halves x2 = 69632 B) then B double-buffer (2x32768)
    __shared__ __align__(16) char smem[69632];
    __shared__ float sChsq[V_];
    __shared__ int scode[128];

    const int tid = threadIdx.x;
    const int tl = tid & 63;
    const int wq = tid >> 6;       // 0..3
    const int ln = tid & 15;       // MFMA col (n) / A row (m)
    const int q = (tid >> 4) & 3;  // quad
    const int b = blockIdx.x >> 5;           // 32 t-tiles of 128 per batch entry
    const int t00 = (blockIdx.x & 31) << 7;  // t-tile start

    _Float16* AhS = (_Float16*)smem;  // [128][136] (+8 pad)
    _Float16* AlS = AhS + 128 * 136;

    // ---- stage chsq into LDS ----
#pragma unroll
    for (int i = 0; i < V_ / 256; ++i) sChsq[tid + i * 256] = chsq[tid + i * 256];

    // ---- stage A tile (128 t x 128 d), f16 split, [t][k] rows ----
#pragma unroll
    for (int th = 0; th < 2; ++th) {
        const int row = th * 64 + tl;
        const float* xp = latents + (size_t)b * D_ * T_ + t00 + row;
#pragma unroll
        for (int i = 0; i < 4; ++i) {
            const int d0 = wq * 32 + i * 8;
            float x[8];
#pragma unroll
            for (int j = 0; j < 8; ++j) x[j] = xp[(size_t)(d0 + j) * T_];
            half8 h, l;
#pragma unroll
            for (int j = 0; j < 8; ++j) {
                _Float16 xh = (_Float16)x[j];
                h[j] = xh;
                l[j] = (_Float16)((x[j] - (float)xh) * 2048.0f);
            }
            *(half8*)(AhS + row * 136 + d0) = h;
            *(half8*)(AlS + row * 136 + d0) = l;
        }
    }
    __syncthreads();

    // ---- extract A fragments to registers (once): wave owns rows wq*32..+32 ----
    half8 ah[4][2], al[4][2];  // [kt][mt] : 64 VGPRs
#pragma unroll
    for (int kt = 0; kt < 4; ++kt)
#pragma unroll
        for (int mt = 0; mt < 2; ++mt) {
            const int row = wq * 32 + mt * 16 + ln;
            ah[kt][mt] = *(const half8*)(AhS + row * 136 + kt * 32 + q * 8);
            al[kt][mt] = *(const half8*)(AlS + row * 136 + kt * 32 + q * 8);
        }
    __syncthreads();  // A region dead -> reuse as B double-buffer

    char* Bb = smem;  // [2][32768]

    float bestF[2][4];
    int bestv[2][4];
#pragma unroll
    for (int mt = 0; mt < 2; ++mt)
#pragma unroll
        for (int r = 0; r < 4; ++r) {
            bestF[mt][r] = 3.0e38f;
            bestv[mt][r] = 0;
        }

    // compute one 32-v chunk from `cb` (16 KB LDS image) into the given accs
    auto compute = [&](const char* cb2, float4v a1[2][2], float4v a2[2][2]) {
#pragma unroll
        for (int mt = 0; mt < 2; ++mt)
#pragma unroll
            for (int ntl = 0; ntl < 2; ++ntl) {
                a1[mt][ntl] = (float4v){0.f, 0.f, 0.f, 0.f};
                a2[mt][ntl] = (float4v){0.f, 0.f, 0.f, 0.f};
            }
#pragma unroll
        for (int kt = 0; kt < 4; ++kt) {
            half8 bh[2], bl[2];
#pragma unroll
            for (int ntl = 0; ntl < 2; ++ntl) {
                const int o = kt * 2048 + ntl * 1024 + tl * 16;  // lane-linear
                bh[ntl] = *(const half8*)(cb2 + o);
                bl[ntl] = *(const half8*)(cb2 + 8192 + o);
            }
#pragma unroll
            for (int ntl = 0; ntl < 2; ++ntl)
#pragma unroll
                for (int mt = 0; mt < 2; ++mt) {
                    a1[mt][ntl] = __builtin_amdgcn_mfma_f32_16x16x32_f16(
                        ah[kt][mt], bh[ntl], a1[mt][ntl], 0, 0, 0);
                    a2[mt][ntl] = __builtin_amdgcn_mfma_f32_16x16x32_f16(
                        ah[kt][mt], bl[ntl], a2[mt][ntl], 0, 0, 0);
                    a2[mt][ntl] = __builtin_amdgcn_mfma_f32_16x16x32_f16(
                        al[kt][mt], bh[ntl], a2[mt][ntl], 0, 0, 0);
                }
        }
    };
    // fold chunk cc's accs into the running argmin; ntl=0 first (lower n ties)
    auto fold = [&](int cc, float4v a1[2][2], float4v a2[2][2]) {
#pragma unroll
        for (int ntl = 0; ntl < 2; ++ntl) {
            const int n = cc * 32 + ntl * 16 + ln;
            const float csq = sChsq[n];
#pragma unroll
            for (int mt = 0; mt < 2; ++mt)
#pragma unroll
                for (int r = 0; r < 4; ++r) {
                    const float score =
                        csq - (a1[mt][ntl][r] + a2[mt][ntl][r] * (1.0f / 2048.0f));
                    if (score < bestF[mt][r]) {  // strict < => lowest v on ties
                        bestF[mt][r] = score;
                        bestv[mt][r] = n;
                    }
                }
        }
    };

    // ---- prologue: DMA pair 0 into buf 0; barrier drains vmcnt ----
    dma_pair(Bb, Bc, 0, wq, tl);
    __syncthreads();

    for (int p = 0; p < 16; ++p) {
        if (p + 1 < 16) dma_pair(Bb + ((p + 1) & 1) * 32768, Bc, p + 1, wq, tl);

        const char* buf = Bb + (p & 1) * 32768;
        float4v accA1[2][2], accA2[2][2], accB1[2][2], accB2[2][2];
        compute(buf, accA1, accA2);          // chunk 2p
        compute(buf + 16384, accB1, accB2);  // chunk 2p+1 (independent)
        fold(2 * p, accA1, accA2);       // co-issues with chunk-B MFMAs
        fold(2 * p + 1, accB1, accB2);   // after A: ascending v preserved
        __syncthreads();  // drain DMA(p+1) + release buf for pair p+2
    }

    // cross-lane argmin over the 16-col group; ties -> lowest v
#pragma unroll
    for (int off = 1; off < 16; off <<= 1) {
#pragma unroll
        for (int mt = 0; mt < 2; ++mt)
#pragma unroll
            for (int r = 0; r < 4; ++r) {
                const float of = __shfl_xor(bestF[mt][r], off, 64);
                const int ov = __shfl_xor(bestv[mt][r], off, 64);
                if (of < bestF[mt][r] || (of == bestF[mt][r] && ov < bestv[mt][r])) {
                    bestF[mt][r] = of;
                    bestv[mt][r] = ov;
                }
            }
    }

    // per-wave complete argmin: lanes ln==0 publish rows m = wq*32+mt*16+q*4+r
    if (ln == 0) {
#pragma unroll
        for (int mt = 0; mt < 2; ++mt)
#pragma unroll
            for (int r = 0; r < 4; ++r) {
                const int m = wq * 32 + mt * 16 + q * 4 + r;
                scode[m] = bestv[mt][r];
                out_codes[(size_t)b * T_ + t00 + m] = (float)bestv[mt][r];
            }
    }
    __syncthreads();

    // gather-write quantized[b, d, t00+row] = codebook[code, d]; coalesced
#pragma unroll
    for (int th = 0; th < 2; ++th) {
        const int row = th * 64 + tl;
        const int code = scode[row];
        const float* crow = codebook + (size_t)code * D_;
        float* qp = out_q + (size_t)b * D_ * T_ + t00 + row;
#pragma unroll
        for (int i = 0; i < 32; ++i) {
            const int d = wq * 32 + i;
            qp[(size_t)d * T_] = crow[d];
        }
    }
}

extern "C" void kernel_launch(void* const* d_in, const int* in_sizes, int n_in,
                              void* d_out, int out_size, void* d_ws, size_t ws_size,
                              hipStream_t stream) {
    const float* latents = (const float*)d_in[0];   // (B, D, T) f32
    const float* codebook = (const float*)d_in[1];  // (V, D) f32

    float* out_codes = (float*)d_out;        // (B, T) codes as f32 values
    float* out_q = (float*)d_out + B_ * T_;  // (B, D, T) quantized f32

    float* chsq = (float*)d_ws;
    char* Bc = (char*)d_ws + 4096;  // 512 KB lane-linear f16 hi/lo image

    split_csq_kernel<<<(V_ * 16) / 256, 256, 0, stream>>>(codebook, Bc, chsq);
    vq_mfma<<<(B_ * T_) / 128, 256, 0, stream>>>(latents, codebook, chsq, Bc, out_codes,
                                                 out_q);
}